// Round 1
// baseline (1571.994 us; speedup 1.0000x reference)
//
#include <hip/hip_runtime.h>
#include <math.h>

#define N_NODE 4096
#define N_EDGE 262144
#define E_TOT (N_EDGE + N_NODE)
#define DD 64
#define NL 3
#define NG 64

__device__ __forceinline__ void atomAddF(float* p, float v) {
#if defined(__HIP_PLATFORM_AMD__)
  unsafeAtomicAdd(p, v);
#else
  atomicAdd(p, v);
#endif
}

// ---------------- CSR build ----------------
__global__ void csr_count_kernel(const int* __restrict__ ei, int* __restrict__ cnt) {
  int e = blockIdx.x * blockDim.x + threadIdx.x;
  if (e >= E_TOT) return;
  int dst = (e < N_EDGE) ? ei[N_EDGE + e] : (e - N_EDGE);
  atomicAdd(&cnt[dst], 1);
}

__global__ void csr_scan_kernel(const int* __restrict__ cnt, int* __restrict__ row_ptr,
                                int* __restrict__ nextp) {
  __shared__ int ps[256];
  __shared__ int ps2[257];
  int t = threadIdx.x;
  int base = t * 16;
  int loc[16];
  int s = 0;
#pragma unroll
  for (int k = 0; k < 16; ++k) { loc[k] = s; s += cnt[base + k]; }
  ps[t] = s;
  __syncthreads();
  if (t == 0) {
    int a = 0;
    for (int u = 0; u < 256; ++u) { ps2[u] = a; a += ps[u]; }
    ps2[256] = a;
  }
  __syncthreads();
  int off = ps2[t];
#pragma unroll
  for (int k = 0; k < 16; ++k) {
    int v = off + loc[k];
    row_ptr[base + k] = v;
    nextp[base + k] = v;
  }
  if (t == 0) row_ptr[N_NODE] = ps2[256];
}

__global__ void csr_fill_kernel(const int* __restrict__ ei, int* __restrict__ nextp,
                                int* __restrict__ csr_src) {
  int e = blockIdx.x * blockDim.x + threadIdx.x;
  if (e >= E_TOT) return;
  int src, dst;
  if (e < N_EDGE) { src = ei[e]; dst = ei[N_EDGE + e]; }
  else { src = dst = e - N_EDGE; }
  int pos = atomicAdd(&nextp[dst], 1);
  csr_src[pos] = src;
}

// ---------------- weight transpose (attn in/out, once) ----------------
__global__ void transpose_w_kernel(const float* __restrict__ win, const float* __restrict__ wout,
                                   float* __restrict__ tin, float* __restrict__ tout) {
  int idx = blockIdx.x * blockDim.x + threadIdx.x;
  if (idx < NL * 192 * 64) {
    int l = idx / (192 * 64), rem = idx % (192 * 64);
    int j = rem / 64, k = rem % 64;
    tin[l * 192 * 64 + k * 192 + j] = win[idx];
  }
  if (idx < NL * 64 * 64) {
    int l = idx / 4096, rem = idx % 4096;
    int j = rem / 64, k = rem % 64;
    tout[l * 4096 + k * 64 + j] = wout[idx];
  }
}

// ---------------- generic linear: C = act(A @ W + b) (+resid) ----------------
// W row-major [K][Nc]. act: 0 none, 1 exact-gelu, 2 relu.
__global__ void linear_kernel(const float* __restrict__ A, const float* __restrict__ W,
                              const float* __restrict__ bias, float* __restrict__ C,
                              const float* __restrict__ resid,
                              int K, int Nc, int act) {
  extern __shared__ float sA[];
  int R = blockDim.x / Nc;
  int r = threadIdx.x / Nc;
  int j = threadIdx.x - r * Nc;
  int row0 = blockIdx.x * R;
  for (int idx = threadIdx.x; idx < R * K; idx += blockDim.x)
    sA[idx] = A[row0 * K + idx];
  __syncthreads();
  int row = row0 + r;
  const float* a = sA + r * K;
  float acc = bias[j];
#pragma unroll 8
  for (int k = 0; k < K; ++k) acc = fmaf(a[k], W[k * Nc + j], acc);
  if (act == 1) acc = 0.5f * acc * (1.0f + erff(acc * 0.70710678118654752f));
  else if (act == 2) acc = fmaxf(acc, 0.0f);
  if (resid) acc += resid[row * Nc + j];
  C[row * Nc + j] = acc;
}

// ---------------- GATv2 aggregate: one wave per dst node, online softmax ----------------
__global__ void gat_agg_kernel(const float* __restrict__ x, const float* __restrict__ xl,
                               const float* __restrict__ xr, const float* __restrict__ att,
                               const float* __restrict__ gbias,
                               const int* __restrict__ row_ptr, const int* __restrict__ csr_src,
                               float* __restrict__ z1) {
  int wave = (blockIdx.x * blockDim.x + threadIdx.x) >> 6;
  int lane = threadIdx.x & 63;
  if (wave >= N_NODE) return;
  int i = wave;
  float xr_d = xr[i * DD + lane];
  float att_d = att[lane];
  float m = -INFINITY, s = 0.f, acc = 0.f;
  int e0 = row_ptr[i], e1 = row_ptr[i + 1];
  for (int e = e0; e < e1; ++e) {
    int src = csr_src[e];
    float xl_d = xl[src * DD + lane];
    float v = xl_d + xr_d;
    float lr = (v > 0.f) ? v : 0.2f * v;
    float p = lr * att_d;
#pragma unroll
    for (int off = 32; off; off >>= 1) p += __shfl_xor(p, off, 64);
    float nm = fmaxf(m, p);
    float corr = expf(m - nm);
    float w = expf(p - nm);
    s = s * corr + w;
    acc = acc * corr + w * xl_d;
    m = nm;
  }
  z1[i * DD + lane] = x[i * DD + lane] + gbias[lane] + acc / s;
}

// ---------------- column stats for BN (sum, sumsq) ----------------
__global__ void colstats_kernel(const float* __restrict__ z, float* __restrict__ stats) {
  int d = threadIdx.x & 63;
  int rg = threadIdx.x >> 6;
  int i0 = blockIdx.x * 128;
  float s = 0.f, q = 0.f;
  for (int i = i0 + rg; i < i0 + 128; i += 4) {
    float v = z[i * DD + d];
    s += v;
    q += v * v;
  }
  atomAddF(&stats[d], s);
  atomAddF(&stats[64 + d], q);
}

// ---------------- BN apply (+optional postadd, +optional relu) ----------------
__global__ void bn_apply_kernel(const float* __restrict__ z, const float* __restrict__ stats,
                                const float* __restrict__ g, const float* __restrict__ b,
                                const float* __restrict__ postadd, float* __restrict__ out,
                                int relu) {
  int idx = blockIdx.x * blockDim.x + threadIdx.x;
  if (idx >= N_NODE * DD) return;
  int d = idx & 63;
  const float invN = 1.0f / (float)N_NODE;
  float mu = stats[d] * invN;
  float var = stats[64 + d] * invN - mu * mu;
  float rstd = rsqrtf(var + 1e-5f);
  float v = (z[idx] - mu) * rstd * g[d] + b[d];
  if (postadd) v += postadd[idx];
  if (relu) v = fmaxf(v, 0.f);
  out[idx] = v;
}

// ---------------- flash attention fp32: grid (N/64, H), block 256 ----------------
#define TJ 256
__global__ void attn_kernel(const float* __restrict__ qkv, float* __restrict__ o) {
  __shared__ __align__(16) float kv[TJ * 32];  // [TJ][16] K then [TJ][16] V
  int h = blockIdx.y;
  int i0 = blockIdx.x * 64;
  int r = threadIdx.x & 63;
  int gq = threadIdx.x >> 6;  // 4 j-groups (one wave each)
  int i = i0 + r;
  float q[16];
#pragma unroll
  for (int c = 0; c < 16; ++c) q[c] = qkv[i * 192 + h * 16 + c] * 0.25f;
  float m = -INFINITY, s = 0.f;
  float acc[16];
#pragma unroll
  for (int c = 0; c < 16; ++c) acc[c] = 0.f;
  for (int j0 = 0; j0 < N_NODE; j0 += TJ) {
    __syncthreads();
    {
      int jj = threadIdx.x;
      const float* kr = qkv + (size_t)(j0 + jj) * 192 + 64 + h * 16;
      const float* vr = qkv + (size_t)(j0 + jj) * 192 + 128 + h * 16;
#pragma unroll
      for (int c = 0; c < 16; c += 4) {
        *(float4*)&kv[jj * 16 + c] = *(const float4*)&kr[c];
        *(float4*)&kv[TJ * 16 + jj * 16 + c] = *(const float4*)&vr[c];
      }
    }
    __syncthreads();
    for (int jt = gq; jt < TJ; jt += 4) {
      const float4* kk = (const float4*)&kv[jt * 16];
      float4 k0 = kk[0], k1 = kk[1], k2 = kk[2], k3 = kk[3];
      float sc = q[0] * k0.x + q[1] * k0.y + q[2] * k0.z + q[3] * k0.w;
      sc += q[4] * k1.x + q[5] * k1.y + q[6] * k1.z + q[7] * k1.w;
      sc += q[8] * k2.x + q[9] * k2.y + q[10] * k2.z + q[11] * k2.w;
      sc += q[12] * k3.x + q[13] * k3.y + q[14] * k3.z + q[15] * k3.w;
      float nm = fmaxf(m, sc);
      float corr = expf(m - nm);
      float p = expf(sc - nm);
      const float4* vv = (const float4*)&kv[TJ * 16 + jt * 16];
      float4 v0 = vv[0], v1 = vv[1], v2 = vv[2], v3 = vv[3];
      s = s * corr + p;
      acc[0] = acc[0] * corr + p * v0.x;  acc[1] = acc[1] * corr + p * v0.y;
      acc[2] = acc[2] * corr + p * v0.z;  acc[3] = acc[3] * corr + p * v0.w;
      acc[4] = acc[4] * corr + p * v1.x;  acc[5] = acc[5] * corr + p * v1.y;
      acc[6] = acc[6] * corr + p * v1.z;  acc[7] = acc[7] * corr + p * v1.w;
      acc[8] = acc[8] * corr + p * v2.x;  acc[9] = acc[9] * corr + p * v2.y;
      acc[10] = acc[10] * corr + p * v2.z; acc[11] = acc[11] * corr + p * v2.w;
      acc[12] = acc[12] * corr + p * v3.x; acc[13] = acc[13] * corr + p * v3.y;
      acc[14] = acc[14] * corr + p * v3.z; acc[15] = acc[15] * corr + p * v3.w;
      m = nm;
    }
  }
  // combine 4 partials per row via LDS (reuse kv)
  __syncthreads();
  float* cb = kv;
  int slot = (r * 4 + gq) * 18;
  cb[slot + 0] = m;
  cb[slot + 1] = s;
#pragma unroll
  for (int c = 0; c < 16; ++c) cb[slot + 2 + c] = acc[c];
  __syncthreads();
  if (gq == 0) {
    float M2 = -INFINITY;
#pragma unroll
    for (int g2 = 0; g2 < 4; ++g2) M2 = fmaxf(M2, cb[(r * 4 + g2) * 18 + 0]);
    float S2 = 0.f;
    float out[16];
#pragma unroll
    for (int c = 0; c < 16; ++c) out[c] = 0.f;
    for (int g2 = 0; g2 < 4; ++g2) {
      int sl = (r * 4 + g2) * 18;
      float w = expf(cb[sl + 0] - M2);
      S2 += cb[sl + 1] * w;
#pragma unroll
      for (int c = 0; c < 16; ++c) out[c] += cb[sl + 2 + c] * w;
    }
    float inv = 1.0f / S2;
#pragma unroll
    for (int c = 0; c < 16; ++c) o[i * DD + h * 16 + c] = out[c] * inv;
  }
}

// ---------------- global mean pool ----------------
__global__ void pool_kernel(const float* __restrict__ x, const int* __restrict__ batch,
                            float* __restrict__ pool, float* __restrict__ pcnt) {
  int idx = blockIdx.x * blockDim.x + threadIdx.x;
  if (idx >= N_NODE * DD) return;
  int i = idx >> 6, d = idx & 63;
  int g = batch[i];
  atomAddF(&pool[g * DD + d], x[idx]);
  if (d == 0) atomAddF(&pcnt[g], 1.0f);
}

// ---------------- final linear + log_softmax ----------------
__global__ void final_kernel(const float* __restrict__ pool, const float* __restrict__ pcnt,
                             const float* __restrict__ fw, const float* __restrict__ fb,
                             float* __restrict__ out) {
  int g = blockIdx.x;
  int d = threadIdx.x;  // 64 threads
  __shared__ float mean[64];
  __shared__ float lg[16];
  float c = fmaxf(pcnt[g], 1.0f);
  mean[d] = pool[g * DD + d] / c;
  __syncthreads();
  if (d < 10) {
    float acc = fb[d];
#pragma unroll 8
    for (int k = 0; k < 64; ++k) acc += mean[k] * fw[k * 10 + d];
    lg[d] = acc;
  }
  __syncthreads();
  if (d == 0) {
    float mx = -INFINITY;
    for (int c2 = 0; c2 < 10; ++c2) mx = fmaxf(mx, lg[c2]);
    float sum = 0.f;
    for (int c2 = 0; c2 < 10; ++c2) sum += expf(lg[c2] - mx);
    lg[10] = mx + logf(sum);
  }
  __syncthreads();
  if (d < 10) out[g * 10 + d] = lg[d] - lg[10];
}

// ---------------- host side ----------------
static void run_linear(const float* A, const float* W, const float* b, float* C,
                       const float* resid, int K, int Nc, int act, hipStream_t s) {
  int R = (Nc == 64) ? 4 : 2;
  int block = Nc * R;
  int grid = N_NODE / R;
  hipLaunchKernelGGL(linear_kernel, dim3(grid), dim3(block), R * K * sizeof(float), s,
                     A, W, b, C, resid, K, Nc, act);
}

extern "C" void kernel_launch(void* const* d_in, const int* in_sizes, int n_in,
                              void* d_out, int out_size, void* d_ws, size_t ws_size,
                              hipStream_t stream) {
  const float* x_in      = (const float*)d_in[0];
  const int*   edge_idx  = (const int*)d_in[1];
  const int*   batch     = (const int*)d_in[2];
  const float* pre_w1    = (const float*)d_in[3];
  const float* pre_b1    = (const float*)d_in[4];
  const float* pre_w2    = (const float*)d_in[5];
  const float* pre_b2    = (const float*)d_in[6];
  const float* gat_wl    = (const float*)d_in[7];
  const float* gat_bl    = (const float*)d_in[8];
  const float* gat_wr    = (const float*)d_in[9];
  const float* gat_br    = (const float*)d_in[10];
  const float* gat_att   = (const float*)d_in[11];
  const float* gat_bias  = (const float*)d_in[12];
  const float* attn_in_w = (const float*)d_in[13];
  const float* attn_in_b = (const float*)d_in[14];
  const float* attn_out_w= (const float*)d_in[15];
  const float* attn_out_b= (const float*)d_in[16];
  const float* bn1_g     = (const float*)d_in[17];
  const float* bn1_b     = (const float*)d_in[18];
  const float* bn2_g     = (const float*)d_in[19];
  const float* bn2_b     = (const float*)d_in[20];
  const float* bn3_g     = (const float*)d_in[21];
  const float* bn3_b     = (const float*)d_in[22];
  const float* mlp_w1    = (const float*)d_in[23];
  const float* mlp_b1    = (const float*)d_in[24];
  const float* mlp_w2    = (const float*)d_in[25];
  const float* mlp_b2    = (const float*)d_in[26];
  const float* fin_w     = (const float*)d_in[27];
  const float* fin_b     = (const float*)d_in[28];
  float* out = (float*)d_out;

  // workspace layout (floats)
  float* ws = (float*)d_ws;
  float* xbuf  = ws;                    // 262144
  float* xlbuf = xbuf  + N_NODE * DD;   // 262144 (also attn o)
  float* xrbuf = xlbuf + N_NODE * DD;   // 262144 (also z2, z3)
  float* z1    = xrbuf + N_NODE * DD;   // 262144 (also comb)
  float* h1n   = z1    + N_NODE * DD;   // 262144
  float* qkv   = h1n   + N_NODE * DD;   // 786432
  float* hid   = qkv   + N_NODE * 192;  // 524288 (also pre intermediate)
  float* tin   = hid   + N_NODE * 128;  // 36864
  float* tout  = tin   + NL * 192 * 64; // 12288
  float* stats = tout  + NL * 64 * 64;  // 128
  float* pool  = stats + 128;           // 4096
  float* pcnt  = pool  + NG * DD;       // 64
  int* cnt     = (int*)(pcnt + NG);     // 4096
  int* row_ptr = cnt + N_NODE;          // 4097
  int* nextp   = row_ptr + N_NODE + 1;  // 4096
  int* csr_src = nextp + N_NODE;        // 266240

  // ---- CSR build (topology constant across layers) ----
  hipMemsetAsync(cnt, 0, N_NODE * sizeof(int), stream);
  hipLaunchKernelGGL(csr_count_kernel, dim3((E_TOT + 255) / 256), dim3(256), 0, stream,
                     edge_idx, cnt);
  hipLaunchKernelGGL(csr_scan_kernel, dim3(1), dim3(256), 0, stream, cnt, row_ptr, nextp);
  hipLaunchKernelGGL(csr_fill_kernel, dim3((E_TOT + 255) / 256), dim3(256), 0, stream,
                     edge_idx, nextp, csr_src);

  // ---- transpose attn weights once ----
  hipLaunchKernelGGL(transpose_w_kernel, dim3((NL * 192 * 64 + 255) / 256), dim3(256), 0, stream,
                     attn_in_w, attn_out_w, tin, tout);

  // ---- preprocess MLP ----
  run_linear(x_in, pre_w1, pre_b1, hid, nullptr, 9, 128, 1, stream);
  run_linear(hid, pre_w2, pre_b2, xbuf, nullptr, 128, 64, 1, stream);

  for (int l = 0; l < NL; ++l) {
    const float* Wl = gat_wl + l * DD * DD;
    const float* bl = gat_bl + l * DD;
    const float* Wr = gat_wr + l * DD * DD;
    const float* br = gat_br + l * DD;
    const float* attv = gat_att + l * DD;
    const float* gbias = gat_bias + l * DD;
    const float* tinl = tin + l * 192 * 64;
    const float* toutl = tout + l * 64 * 64;

    // local GATv2
    run_linear(xbuf, Wl, bl, xlbuf, nullptr, 64, 64, 0, stream);
    run_linear(xbuf, Wr, br, xrbuf, nullptr, 64, 64, 0, stream);
    hipLaunchKernelGGL(gat_agg_kernel, dim3(N_NODE / 4), dim3(256), 0, stream,
                       xbuf, xlbuf, xrbuf, attv, gbias, row_ptr, csr_src, z1);
    hipMemsetAsync(stats, 0, 128 * sizeof(float), stream);
    hipLaunchKernelGGL(colstats_kernel, dim3(32), dim3(256), 0, stream, z1, stats);
    hipLaunchKernelGGL(bn_apply_kernel, dim3(N_NODE * DD / 256), dim3(256), 0, stream,
                       z1, stats, bn1_g + l * DD, bn1_b + l * DD, (const float*)nullptr, h1n, 0);

    // global attention
    run_linear(xbuf, tinl, attn_in_b + l * 192, qkv, nullptr, 64, 192, 0, stream);
    hipLaunchKernelGGL(attn_kernel, dim3(N_NODE / 64, 4), dim3(256), 0, stream, qkv, xlbuf);
    run_linear(xlbuf, toutl, attn_out_b + l * DD, xrbuf, xbuf, 64, 64, 0, stream);  // z2 = proj + x
    hipMemsetAsync(stats, 0, 128 * sizeof(float), stream);
    hipLaunchKernelGGL(colstats_kernel, dim3(32), dim3(256), 0, stream, xrbuf, stats);
    hipLaunchKernelGGL(bn_apply_kernel, dim3(N_NODE * DD / 256), dim3(256), 0, stream,
                       xrbuf, stats, bn2_g + l * DD, bn2_b + l * DD, h1n, z1, 0);  // comb = bn2(z2)+h1n

    // MLP
    run_linear(z1, mlp_w1 + l * 64 * 128, mlp_b1 + l * 128, hid, nullptr, 64, 128, 2, stream);
    run_linear(hid, mlp_w2 + l * 128 * 64, mlp_b2 + l * DD, xrbuf, z1, 128, 64, 0, stream); // z3
    hipMemsetAsync(stats, 0, 128 * sizeof(float), stream);
    hipLaunchKernelGGL(colstats_kernel, dim3(32), dim3(256), 0, stream, xrbuf, stats);
    hipLaunchKernelGGL(bn_apply_kernel, dim3(N_NODE * DD / 256), dim3(256), 0, stream,
                       xrbuf, stats, bn3_g + l * DD, bn3_b + l * DD, (const float*)nullptr, xbuf, 1);
  }

  // ---- pool + final ----
  hipMemsetAsync(pool, 0, (NG * DD + NG) * sizeof(float), stream);
  hipLaunchKernelGGL(pool_kernel, dim3(N_NODE * DD / 256), dim3(256), 0, stream,
                     xbuf, batch, pool, pcnt);
  hipLaunchKernelGGL(final_kernel, dim3(NG), dim3(64), 0, stream, pool, pcnt, fin_w, fin_b, out);
}

// Round 2
// 909.438 us; speedup vs baseline: 1.7285x; 1.7285x over previous
//
#include <hip/hip_runtime.h>
#include <math.h>

#define N_NODE 4096
#define N_EDGE 262144
#define E_TOT (N_EDGE + N_NODE)
#define DD 64
#define NL 3
#define NG 64

__device__ __forceinline__ void atomAddF(float* p, float v) {
#if defined(__HIP_PLATFORM_AMD__)
  unsafeAtomicAdd(p, v);
#else
  atomicAdd(p, v);
#endif
}

// ---------------- CSR build ----------------
__global__ void csr_count_kernel(const int* __restrict__ ei, int* __restrict__ cnt) {
  int e = blockIdx.x * blockDim.x + threadIdx.x;
  if (e >= E_TOT) return;
  int dst = (e < N_EDGE) ? ei[N_EDGE + e] : (e - N_EDGE);
  atomicAdd(&cnt[dst], 1);
}

__global__ void csr_scan_kernel(const int* __restrict__ cnt, int* __restrict__ row_ptr,
                                int* __restrict__ nextp) {
  __shared__ int ps[256];
  __shared__ int ps2[257];
  int t = threadIdx.x;
  int base = t * 16;
  int loc[16];
  int s = 0;
#pragma unroll
  for (int k = 0; k < 16; ++k) { loc[k] = s; s += cnt[base + k]; }
  ps[t] = s;
  __syncthreads();
  if (t == 0) {
    int a = 0;
    for (int u = 0; u < 256; ++u) { ps2[u] = a; a += ps[u]; }
    ps2[256] = a;
  }
  __syncthreads();
  int off = ps2[t];
#pragma unroll
  for (int k = 0; k < 16; ++k) {
    int v = off + loc[k];
    row_ptr[base + k] = v;
    nextp[base + k] = v;
  }
  if (t == 0) row_ptr[N_NODE] = ps2[256];
}

__global__ void csr_fill_kernel(const int* __restrict__ ei, int* __restrict__ nextp,
                                int* __restrict__ csr_src) {
  int e = blockIdx.x * blockDim.x + threadIdx.x;
  if (e >= E_TOT) return;
  int src, dst;
  if (e < N_EDGE) { src = ei[e]; dst = ei[N_EDGE + e]; }
  else { src = dst = e - N_EDGE; }
  int pos = atomicAdd(&nextp[dst], 1);
  csr_src[pos] = src;
}

// ---------------- weight transpose (attn in/out, once) ----------------
__global__ void transpose_w_kernel(const float* __restrict__ win, const float* __restrict__ wout,
                                   float* __restrict__ tin, float* __restrict__ tout) {
  int idx = blockIdx.x * blockDim.x + threadIdx.x;
  if (idx < NL * 192 * 64) {
    int l = idx / (192 * 64), rem = idx % (192 * 64);
    int j = rem / 64, k = rem % 64;
    tin[l * 192 * 64 + k * 192 + j] = win[idx];
  }
  if (idx < NL * 64 * 64) {
    int l = idx / 4096, rem = idx % 4096;
    int j = rem / 64, k = rem % 64;
    tout[l * 4096 + k * 64 + j] = wout[idx];
  }
}

// ---------------- generic linear: C = act(A @ W + b) (+resid) ----------------
__global__ void linear_kernel(const float* __restrict__ A, const float* __restrict__ W,
                              const float* __restrict__ bias, float* __restrict__ C,
                              const float* __restrict__ resid,
                              int K, int Nc, int act) {
  extern __shared__ float sA[];
  int R = blockDim.x / Nc;
  int r = threadIdx.x / Nc;
  int j = threadIdx.x - r * Nc;
  int row0 = blockIdx.x * R;
  for (int idx = threadIdx.x; idx < R * K; idx += blockDim.x)
    sA[idx] = A[row0 * K + idx];
  __syncthreads();
  int row = row0 + r;
  const float* a = sA + r * K;
  float acc = bias[j];
#pragma unroll 8
  for (int k = 0; k < K; ++k) acc = fmaf(a[k], W[k * Nc + j], acc);
  if (act == 1) acc = 0.5f * acc * (1.0f + erff(acc * 0.70710678118654752f));
  else if (act == 2) acc = fmaxf(acc, 0.0f);
  if (resid) acc += resid[row * Nc + j];
  C[row * Nc + j] = acc;
}

// ---------------- GATv2 aggregate ----------------
__global__ void gat_agg_kernel(const float* __restrict__ x, const float* __restrict__ xl,
                               const float* __restrict__ xr, const float* __restrict__ att,
                               const float* __restrict__ gbias,
                               const int* __restrict__ row_ptr, const int* __restrict__ csr_src,
                               float* __restrict__ z1) {
  int wave = (blockIdx.x * blockDim.x + threadIdx.x) >> 6;
  int lane = threadIdx.x & 63;
  if (wave >= N_NODE) return;
  int i = wave;
  float xr_d = xr[i * DD + lane];
  float att_d = att[lane];
  float m = -INFINITY, s = 0.f, acc = 0.f;
  int e0 = row_ptr[i], e1 = row_ptr[i + 1];
  for (int e = e0; e < e1; ++e) {
    int src = csr_src[e];
    float xl_d = xl[src * DD + lane];
    float v = xl_d + xr_d;
    float lr = (v > 0.f) ? v : 0.2f * v;
    float p = lr * att_d;
#pragma unroll
    for (int off = 32; off; off >>= 1) p += __shfl_xor(p, off, 64);
    float nm = fmaxf(m, p);
    float corr = __expf(m - nm);
    float w = __expf(p - nm);
    s = s * corr + w;
    acc = acc * corr + w * xl_d;
    m = nm;
  }
  z1[i * DD + lane] = x[i * DD + lane] + gbias[lane] + acc / s;
}

// ---------------- column stats for BN ----------------
__global__ void colstats_kernel(const float* __restrict__ z, float* __restrict__ stats) {
  int d = threadIdx.x & 63;
  int rg = threadIdx.x >> 6;
  int i0 = blockIdx.x * 128;
  float s = 0.f, q = 0.f;
  for (int i = i0 + rg; i < i0 + 128; i += 4) {
    float v = z[i * DD + d];
    s += v;
    q += v * v;
  }
  atomAddF(&stats[d], s);
  atomAddF(&stats[64 + d], q);
}

// ---------------- BN apply ----------------
__global__ void bn_apply_kernel(const float* __restrict__ z, const float* __restrict__ stats,
                                const float* __restrict__ g, const float* __restrict__ b,
                                const float* __restrict__ postadd, float* __restrict__ out,
                                int relu) {
  int idx = blockIdx.x * blockDim.x + threadIdx.x;
  if (idx >= N_NODE * DD) return;
  int d = idx & 63;
  const float invN = 1.0f / (float)N_NODE;
  float mu = stats[d] * invN;
  float var = stats[64 + d] * invN - mu * mu;
  float rstd = rsqrtf(var + 1e-5f);
  float v = (z[idx] - mu) * rstd * g[d] + b[d];
  if (postadd) v += postadd[idx];
  if (relu) v = fmaxf(v, 0.f);
  out[idx] = v;
}

// ---------------- K row-norm max per head (for safe fixed softmax shift) ----------------
__global__ void knorm_kernel(const float* __restrict__ qkv, int* __restrict__ kmax) {
  __shared__ int lmax[4];
  int tid = threadIdx.x;
  if (tid < 4) lmax[tid] = 0;
  __syncthreads();
  int idx = blockIdx.x * 256 + tid;   // (j, h): 16384 items
  int j = idx >> 2, h = idx & 3;
  const float* kr = qkv + (size_t)j * 192 + 64 + h * 16;
  float n2 = 0.f;
#pragma unroll
  for (int c = 0; c < 16; ++c) { float v = kr[c]; n2 = fmaf(v, v, n2); }
  atomicMax(&lmax[h], __float_as_int(sqrtf(n2)));  // norms >= 0: int order == float order
  __syncthreads();
  if (tid < 4) atomicMax(&kmax[tid], lmax[tid]);
}

// ---------------- flash attention fp32, fixed shift, j-split ----------------
// grid (N/64, H, JS=4), block 256 (4 waves). lane = row, waves stride over j.
#define TJ 256
__global__ void attn_kernel(const float* __restrict__ qkv, const int* __restrict__ kmax,
                            float* __restrict__ accS, float* __restrict__ accO) {
  __shared__ __align__(16) float kv[TJ * 32];  // [TJ][16] K then [TJ][16] V
  int h = blockIdx.y;
  int js = blockIdx.z;
  int i0 = blockIdx.x * 64;
  int r = threadIdx.x & 63;
  int gq = threadIdx.x >> 6;
  int i = i0 + r;
  float q[16];
#pragma unroll
  for (int c = 0; c < 16; ++c) q[c] = qkv[(size_t)i * 192 + h * 16 + c] * 0.25f;
  float qn2 = 0.f;
#pragma unroll
  for (int c = 0; c < 16; ++c) qn2 = fmaf(q[c], q[c], qn2);
  float m = sqrtf(qn2) * __int_as_float(kmax[h]);  // >= max_j score (Cauchy-Schwarz)
  float s = 0.f;
  float acc[16];
#pragma unroll
  for (int c = 0; c < 16; ++c) acc[c] = 0.f;

  for (int t = 0; t < 4; ++t) {
    int j0 = js * 1024 + t * TJ;
    __syncthreads();
    {
      int jj = threadIdx.x;
      const float* kr = qkv + (size_t)(j0 + jj) * 192 + 64 + h * 16;
      const float* vr = qkv + (size_t)(j0 + jj) * 192 + 128 + h * 16;
#pragma unroll
      for (int c = 0; c < 16; c += 4) {
        *(float4*)&kv[jj * 16 + c] = *(const float4*)&kr[c];
        *(float4*)&kv[TJ * 16 + jj * 16 + c] = *(const float4*)&vr[c];
      }
    }
    __syncthreads();
    for (int jt = gq; jt < TJ; jt += 4) {
      const float4* kk = (const float4*)&kv[jt * 16];
      float4 k0 = kk[0], k1 = kk[1], k2 = kk[2], k3 = kk[3];
      float s0 = q[0] * k0.x + q[1] * k0.y + q[2] * k0.z + q[3] * k0.w;
      float s1 = q[4] * k1.x + q[5] * k1.y + q[6] * k1.z + q[7] * k1.w;
      float s2 = q[8] * k2.x + q[9] * k2.y + q[10] * k2.z + q[11] * k2.w;
      float s3 = q[12] * k3.x + q[13] * k3.y + q[14] * k3.z + q[15] * k3.w;
      float p = __expf((s0 + s1) + (s2 + s3) - m);
      const float4* vv = (const float4*)&kv[TJ * 16 + jt * 16];
      float4 v0 = vv[0], v1 = vv[1], v2 = vv[2], v3 = vv[3];
      s += p;
      acc[0] = fmaf(p, v0.x, acc[0]);  acc[1] = fmaf(p, v0.y, acc[1]);
      acc[2] = fmaf(p, v0.z, acc[2]);  acc[3] = fmaf(p, v0.w, acc[3]);
      acc[4] = fmaf(p, v1.x, acc[4]);  acc[5] = fmaf(p, v1.y, acc[5]);
      acc[6] = fmaf(p, v1.z, acc[6]);  acc[7] = fmaf(p, v1.w, acc[7]);
      acc[8] = fmaf(p, v2.x, acc[8]);  acc[9] = fmaf(p, v2.y, acc[9]);
      acc[10] = fmaf(p, v2.z, acc[10]); acc[11] = fmaf(p, v2.w, acc[11]);
      acc[12] = fmaf(p, v3.x, acc[12]); acc[13] = fmaf(p, v3.y, acc[13]);
      acc[14] = fmaf(p, v3.z, acc[14]); acc[15] = fmaf(p, v3.w, acc[15]);
    }
  }
  // block-combine 4 waves (pure sums since m is fixed per row), then atomics
  __syncthreads();
  float* cb = kv;  // [4][17][64]
  cb[(gq * 17 + 16) * 64 + r] = s;
#pragma unroll
  for (int c = 0; c < 16; ++c) cb[(gq * 17 + c) * 64 + r] = acc[c];
  __syncthreads();
  if (gq == 0) {
    float S = 0.f;
#pragma unroll
    for (int g2 = 0; g2 < 4; ++g2) S += cb[(g2 * 17 + 16) * 64 + r];
    atomAddF(&accS[h * N_NODE + i], S);
#pragma unroll
    for (int c = 0; c < 16; ++c) {
      float A = 0.f;
#pragma unroll
      for (int g2 = 0; g2 < 4; ++g2) A += cb[(g2 * 17 + c) * 64 + r];
      atomAddF(&accO[(h * 16 + c) * N_NODE + i], A);
    }
  }
}

// o[i][d] = accO[d][i] / accS[h][i]
__global__ void attn_norm_kernel(const float* __restrict__ accO, const float* __restrict__ accS,
                                 float* __restrict__ o) {
  int idx = blockIdx.x * 256 + threadIdx.x;
  int i = idx >> 6, d = idx & 63, h = d >> 4;
  o[idx] = accO[d * N_NODE + i] / accS[h * N_NODE + i];
}

// ---------------- global mean pool ----------------
__global__ void pool_kernel(const float* __restrict__ x, const int* __restrict__ batch,
                            float* __restrict__ pool, float* __restrict__ pcnt) {
  int idx = blockIdx.x * blockDim.x + threadIdx.x;
  if (idx >= N_NODE * DD) return;
  int i = idx >> 6, d = idx & 63;
  int g = batch[i];
  atomAddF(&pool[g * DD + d], x[idx]);
  if (d == 0) atomAddF(&pcnt[g], 1.0f);
}

// ---------------- final linear + log_softmax ----------------
__global__ void final_kernel(const float* __restrict__ pool, const float* __restrict__ pcnt,
                             const float* __restrict__ fw, const float* __restrict__ fb,
                             float* __restrict__ out) {
  int g = blockIdx.x;
  int d = threadIdx.x;  // 64 threads
  __shared__ float mean[64];
  __shared__ float lg[16];
  float c = fmaxf(pcnt[g], 1.0f);
  mean[d] = pool[g * DD + d] / c;
  __syncthreads();
  if (d < 10) {
    float acc = fb[d];
#pragma unroll 8
    for (int k = 0; k < 64; ++k) acc += mean[k] * fw[k * 10 + d];
    lg[d] = acc;
  }
  __syncthreads();
  if (d == 0) {
    float mx = -INFINITY;
    for (int c2 = 0; c2 < 10; ++c2) mx = fmaxf(mx, lg[c2]);
    float sum = 0.f;
    for (int c2 = 0; c2 < 10; ++c2) sum += expf(lg[c2] - mx);
    lg[10] = mx + logf(sum);
  }
  __syncthreads();
  if (d < 10) out[g * 10 + d] = lg[d] - lg[10];
}

// ---------------- host side ----------------
static void run_linear(const float* A, const float* W, const float* b, float* C,
                       const float* resid, int K, int Nc, int act, hipStream_t s) {
  int R = (Nc == 64) ? 4 : 2;
  int block = Nc * R;
  int grid = N_NODE / R;
  hipLaunchKernelGGL(linear_kernel, dim3(grid), dim3(block), R * K * sizeof(float), s,
                     A, W, b, C, resid, K, Nc, act);
}

extern "C" void kernel_launch(void* const* d_in, const int* in_sizes, int n_in,
                              void* d_out, int out_size, void* d_ws, size_t ws_size,
                              hipStream_t stream) {
  const float* x_in      = (const float*)d_in[0];
  const int*   edge_idx  = (const int*)d_in[1];
  const int*   batch     = (const int*)d_in[2];
  const float* pre_w1    = (const float*)d_in[3];
  const float* pre_b1    = (const float*)d_in[4];
  const float* pre_w2    = (const float*)d_in[5];
  const float* pre_b2    = (const float*)d_in[6];
  const float* gat_wl    = (const float*)d_in[7];
  const float* gat_bl    = (const float*)d_in[8];
  const float* gat_wr    = (const float*)d_in[9];
  const float* gat_br    = (const float*)d_in[10];
  const float* gat_att   = (const float*)d_in[11];
  const float* gat_bias  = (const float*)d_in[12];
  const float* attn_in_w = (const float*)d_in[13];
  const float* attn_in_b = (const float*)d_in[14];
  const float* attn_out_w= (const float*)d_in[15];
  const float* attn_out_b= (const float*)d_in[16];
  const float* bn1_g     = (const float*)d_in[17];
  const float* bn1_b     = (const float*)d_in[18];
  const float* bn2_g     = (const float*)d_in[19];
  const float* bn2_b     = (const float*)d_in[20];
  const float* bn3_g     = (const float*)d_in[21];
  const float* bn3_b     = (const float*)d_in[22];
  const float* mlp_w1    = (const float*)d_in[23];
  const float* mlp_b1    = (const float*)d_in[24];
  const float* mlp_w2    = (const float*)d_in[25];
  const float* mlp_b2    = (const float*)d_in[26];
  const float* fin_w     = (const float*)d_in[27];
  const float* fin_b     = (const float*)d_in[28];
  float* out = (float*)d_out;

  // workspace layout (floats)
  float* ws = (float*)d_ws;
  float* xbuf  = ws;                    // 262144
  float* xlbuf = xbuf  + N_NODE * DD;   // 262144 (attn o)
  float* xrbuf = xlbuf + N_NODE * DD;   // 262144 (z2, z3)
  float* z1    = xrbuf + N_NODE * DD;   // 262144 (comb)
  float* h1n   = z1    + N_NODE * DD;   // 262144
  float* qkv   = h1n   + N_NODE * DD;   // 786432
  float* hid   = qkv   + N_NODE * 192;  // 524288
  float* tin   = hid   + N_NODE * 128;  // 36864
  float* tout  = tin   + NL * 192 * 64; // 12288
  // ---- contiguous zero region (single memset per launch) ----
  float* zr    = tout  + NL * 64 * 64;
  int*   cnt   = (int*)zr;              // 4096
  float* stats = zr + 4096;             // 1152 (9 slots x 128)
  float* pool  = stats + 9 * 128;       // 4096
  float* pcnt  = pool + NG * DD;        // 64
  int*   kmax  = (int*)(pcnt + NG);     // 4
  float* accS  = (float*)(kmax + 4);    // 16384
  float* accO  = accS + 4 * N_NODE;     // 262144
  size_t zr_elems = 4096 + 1152 + 4096 + 64 + 4 + 16384 + 262144;
  // ---- after zero region ----
  float* zend   = accO + 64 * N_NODE;
  int* row_ptr = (int*)zend;            // 4097
  int* nextp   = row_ptr + N_NODE + 1;  // 4096
  int* csr_src = nextp + N_NODE;        // 266240

  hipMemsetAsync(zr, 0, zr_elems * sizeof(float), stream);

  // ---- CSR build ----
  hipLaunchKernelGGL(csr_count_kernel, dim3((E_TOT + 255) / 256), dim3(256), 0, stream,
                     edge_idx, cnt);
  hipLaunchKernelGGL(csr_scan_kernel, dim3(1), dim3(256), 0, stream, cnt, row_ptr, nextp);
  hipLaunchKernelGGL(csr_fill_kernel, dim3((E_TOT + 255) / 256), dim3(256), 0, stream,
                     edge_idx, nextp, csr_src);

  // ---- transpose attn weights once ----
  hipLaunchKernelGGL(transpose_w_kernel, dim3((NL * 192 * 64 + 255) / 256), dim3(256), 0, stream,
                     attn_in_w, attn_out_w, tin, tout);

  // ---- preprocess MLP ----
  run_linear(x_in, pre_w1, pre_b1, hid, nullptr, 9, 128, 1, stream);
  run_linear(hid, pre_w2, pre_b2, xbuf, nullptr, 128, 64, 1, stream);

  for (int l = 0; l < NL; ++l) {
    const float* Wl = gat_wl + l * DD * DD;
    const float* bl = gat_bl + l * DD;
    const float* Wr = gat_wr + l * DD * DD;
    const float* br = gat_br + l * DD;
    const float* attv = gat_att + l * DD;
    const float* gbias = gat_bias + l * DD;
    const float* tinl = tin + l * 192 * 64;
    const float* toutl = tout + l * 64 * 64;
    float* st1 = stats + (l * 3 + 0) * 128;
    float* st2 = stats + (l * 3 + 1) * 128;
    float* st3 = stats + (l * 3 + 2) * 128;

    // local GATv2
    run_linear(xbuf, Wl, bl, xlbuf, nullptr, 64, 64, 0, stream);
    run_linear(xbuf, Wr, br, xrbuf, nullptr, 64, 64, 0, stream);
    hipLaunchKernelGGL(gat_agg_kernel, dim3(N_NODE / 4), dim3(256), 0, stream,
                       xbuf, xlbuf, xrbuf, attv, gbias, row_ptr, csr_src, z1);
    hipLaunchKernelGGL(colstats_kernel, dim3(32), dim3(256), 0, stream, z1, st1);
    hipLaunchKernelGGL(bn_apply_kernel, dim3(N_NODE * DD / 256), dim3(256), 0, stream,
                       z1, st1, bn1_g + l * DD, bn1_b + l * DD, (const float*)nullptr, h1n, 0);

    // global attention
    run_linear(xbuf, tinl, attn_in_b + l * 192, qkv, nullptr, 64, 192, 0, stream);
    hipLaunchKernelGGL(knorm_kernel, dim3(64), dim3(256), 0, stream, qkv, kmax + 0);
    hipLaunchKernelGGL(attn_kernel, dim3(N_NODE / 64, 4, 4), dim3(256), 0, stream,
                       qkv, kmax, accS, accO);
    hipLaunchKernelGGL(attn_norm_kernel, dim3(N_NODE * DD / 256), dim3(256), 0, stream,
                       accO, accS, xlbuf);
    // re-zero acc for next layer is NOT needed within this layer; zero for next layer:
    if (l + 1 < NL) {
      hipMemsetAsync(kmax, 0, (4 + 4 * N_NODE + 64 * N_NODE) * sizeof(float) + 0, stream);
    }
    run_linear(xlbuf, toutl, attn_out_b + l * DD, xrbuf, xbuf, 64, 64, 0, stream);  // z2 = proj + x
    hipLaunchKernelGGL(colstats_kernel, dim3(32), dim3(256), 0, stream, xrbuf, st2);
    hipLaunchKernelGGL(bn_apply_kernel, dim3(N_NODE * DD / 256), dim3(256), 0, stream,
                       xrbuf, st2, bn2_g + l * DD, bn2_b + l * DD, h1n, z1, 0);  // comb

    // MLP
    run_linear(z1, mlp_w1 + l * 64 * 128, mlp_b1 + l * 128, hid, nullptr, 64, 128, 2, stream);
    run_linear(hid, mlp_w2 + l * 128 * 64, mlp_b2 + l * DD, xrbuf, z1, 128, 64, 0, stream); // z3
    hipLaunchKernelGGL(colstats_kernel, dim3(32), dim3(256), 0, stream, xrbuf, st3);
    hipLaunchKernelGGL(bn_apply_kernel, dim3(N_NODE * DD / 256), dim3(256), 0, stream,
                       xrbuf, st3, bn3_g + l * DD, bn3_b + l * DD, (const float*)nullptr, xbuf, 1);
  }

  // ---- pool + final ----
  hipLaunchKernelGGL(pool_kernel, dim3(N_NODE * DD / 256), dim3(256), 0, stream,
                     xbuf, batch, pool, pcnt);
  hipLaunchKernelGGL(final_kernel, dim3(NG), dim3(64), 0, stream, pool, pcnt, fin_w, fin_b, out);
}

// Round 5
// 769.822 us; speedup vs baseline: 2.0420x; 1.1814x over previous
//
#include <hip/hip_runtime.h>
#include <math.h>

#define N_NODE 4096
#define N_EDGE 262144
#define E_TOT (N_EDGE + N_NODE)
#define DD 64
#define NL 3
#define NG 64

typedef __fp16 h2_t __attribute__((ext_vector_type(2)));
union H2x4 { uint4 u; h2_t h[4]; };

__device__ __forceinline__ void atomAddF(float* p, float v) {
#if defined(__HIP_PLATFORM_AMD__)
  unsafeAtomicAdd(p, v);
#else
  atomicAdd(p, v);
#endif
}

// ---------------- CSR build ----------------
__global__ void csr_count_kernel(const int* __restrict__ ei, int* __restrict__ cnt) {
  int e = blockIdx.x * blockDim.x + threadIdx.x;
  if (e >= E_TOT) return;
  int dst = (e < N_EDGE) ? ei[N_EDGE + e] : (e - N_EDGE);
  atomicAdd(&cnt[dst], 1);
}

__global__ void csr_scan_kernel(const int* __restrict__ cnt, int* __restrict__ row_ptr,
                                int* __restrict__ nextp) {
  __shared__ int ps[256];
  __shared__ int ps2[257];
  int t = threadIdx.x;
  int base = t * 16;
  int loc[16];
  int s = 0;
#pragma unroll
  for (int k = 0; k < 16; ++k) { loc[k] = s; s += cnt[base + k]; }
  ps[t] = s;
  __syncthreads();
  if (t == 0) {
    int a = 0;
    for (int u = 0; u < 256; ++u) { ps2[u] = a; a += ps[u]; }
    ps2[256] = a;
  }
  __syncthreads();
  int off = ps2[t];
#pragma unroll
  for (int k = 0; k < 16; ++k) {
    int v = off + loc[k];
    row_ptr[base + k] = v;
    nextp[base + k] = v;
  }
  if (t == 0) row_ptr[N_NODE] = ps2[256];
}

__global__ void csr_fill_kernel(const int* __restrict__ ei, int* __restrict__ nextp,
                                int* __restrict__ csr_src) {
  int e = blockIdx.x * blockDim.x + threadIdx.x;
  if (e >= E_TOT) return;
  int src, dst;
  if (e < N_EDGE) { src = ei[e]; dst = ei[N_EDGE + e]; }
  else { src = dst = e - N_EDGE; }
  int pos = atomicAdd(&nextp[dst], 1);
  csr_src[pos] = src;
}

// ---------------- build combined weights (once) ----------------
// cw[l][k][320]: j<64 gat_wl, j<128 gat_wr, else attn_in_w^T. cb[l][320]. tout = attn_out_w^T.
__global__ void build_w_kernel(const float* __restrict__ wl, const float* __restrict__ bl,
                               const float* __restrict__ wr, const float* __restrict__ br,
                               const float* __restrict__ win, const float* __restrict__ bin,
                               const float* __restrict__ wout,
                               float* __restrict__ cw, float* __restrict__ cbias,
                               float* __restrict__ tout) {
  int idx = blockIdx.x * blockDim.x + threadIdx.x;
  if (idx < NL * 64 * 320) {
    int l = idx / 20480, rem = idx % 20480;
    int k = rem / 320, j = rem % 320;
    float v;
    if (j < 64) v = wl[l * 4096 + k * 64 + j];
    else if (j < 128) v = wr[l * 4096 + k * 64 + (j - 64)];
    else v = win[l * 12288 + (j - 128) * 64 + k];
    cw[idx] = v;
  }
  if (idx < NL * 320) {
    int l = idx / 320, j = idx % 320;
    float v;
    if (j < 64) v = bl[l * 64 + j];
    else if (j < 128) v = br[l * 64 + (j - 64)];
    else v = bin[l * 192 + (j - 128)];
    cbias[idx] = v;
  }
  if (idx < NL * 4096) {
    int l = idx / 4096, rem = idx % 4096;
    int k = rem / 64, j = rem % 64;
    tout[l * 4096 + k * 64 + j] = wout[l * 4096 + j * 64 + k];
  }
}

// ---------------- generic linear: act(A@W+b)(+resid), optional split outputs ----------------
__global__ void linear_kernel(const float* __restrict__ A, const float* __restrict__ W,
                              const float* __restrict__ bias, float* __restrict__ C,
                              float* __restrict__ C2, int split,
                              const float* __restrict__ resid,
                              int K, int Nc, int act) {
  extern __shared__ float sA[];
  int R = blockDim.x / Nc;
  int r = threadIdx.x / Nc;
  int j = threadIdx.x - r * Nc;
  int row0 = blockIdx.x * R;
  for (int idx = threadIdx.x; idx < R * K; idx += blockDim.x)
    sA[idx] = A[row0 * K + idx];
  __syncthreads();
  int row = row0 + r;
  const float* a = sA + r * K;
  float acc = bias[j];
#pragma unroll 8
  for (int k = 0; k < K; ++k) acc = fmaf(a[k], W[k * Nc + j], acc);
  if (act == 1) acc = 0.5f * acc * (1.0f + erff(acc * 0.70710678118654752f));
  else if (act == 2) acc = fmaxf(acc, 0.0f);
  if (resid) acc += resid[row * Nc + j];
  if (j < split) C[row * split + j] = acc;
  else C2[row * (Nc - split) + (j - split)] = acc;
}

// ---------------- GATv2 aggregate (xl|xr packed [4096][128]) ----------------
__global__ void gat_agg_kernel(const float* __restrict__ x, const float* __restrict__ xlr,
                               const float* __restrict__ att, const float* __restrict__ gbias,
                               const int* __restrict__ row_ptr, const int* __restrict__ csr_src,
                               float* __restrict__ z1) {
  int wave = (blockIdx.x * blockDim.x + threadIdx.x) >> 6;
  int lane = threadIdx.x & 63;
  if (wave >= N_NODE) return;
  int i = wave;
  float xr_d = xlr[i * 128 + 64 + lane];
  float att_d = att[lane];
  float m = -INFINITY, s = 0.f, acc = 0.f;
  int e0 = row_ptr[i], e1 = row_ptr[i + 1];
  for (int e = e0; e < e1; ++e) {
    int src = csr_src[e];
    float xl_d = xlr[src * 128 + lane];
    float v = xl_d + xr_d;
    float lr = (v > 0.f) ? v : 0.2f * v;
    float p = lr * att_d;
#pragma unroll
    for (int off = 32; off; off >>= 1) p += __shfl_xor(p, off, 64);
    float nm = fmaxf(m, p);
    float corr = __expf(m - nm);
    float w = __expf(p - nm);
    s = s * corr + w;
    acc = acc * corr + w * xl_d;
    m = nm;
  }
  z1[i * DD + lane] = x[i * DD + lane] + gbias[lane] + acc / s;
}

// ---------------- column stats for BN ----------------
__global__ void colstats_kernel(const float* __restrict__ z, float* __restrict__ stats) {
  int d = threadIdx.x & 63;
  int rg = threadIdx.x >> 6;
  int i0 = blockIdx.x * 128;
  float s = 0.f, q = 0.f;
  for (int i = i0 + rg; i < i0 + 128; i += 4) {
    float v = z[i * DD + d];
    s += v;
    q += v * v;
  }
  atomAddF(&stats[d], s);
  atomAddF(&stats[64 + d], q);
}

// ---------------- BN apply (bn3 + relu) ----------------
__global__ void bn_apply_kernel(const float* __restrict__ z, const float* __restrict__ stats,
                                const float* __restrict__ g, const float* __restrict__ b,
                                float* __restrict__ out, int relu) {
  int idx = blockIdx.x * blockDim.x + threadIdx.x;
  if (idx >= N_NODE * DD) return;
  int d = idx & 63;
  const float invN = 1.0f / (float)N_NODE;
  float mu = stats[d] * invN;
  float var = stats[64 + d] * invN - mu * mu;
  float rstd = rsqrtf(var + 1e-5f);
  float v = (z[idx] - mu) * rstd * g[d] + b[d];
  if (relu) v = fmaxf(v, 0.f);
  out[idx] = v;
}

// ---------------- fused bn1(z1)+bn2(z2) -> comb ----------------
__global__ void bnbn_kernel(const float* __restrict__ z1, const float* __restrict__ st1,
                            const float* __restrict__ g1, const float* __restrict__ b1,
                            const float* __restrict__ z2, const float* __restrict__ st2,
                            const float* __restrict__ g2, const float* __restrict__ b2,
                            float* __restrict__ comb) {
  int idx = blockIdx.x * blockDim.x + threadIdx.x;
  if (idx >= N_NODE * DD) return;
  int d = idx & 63;
  const float invN = 1.0f / (float)N_NODE;
  float mu1 = st1[d] * invN;
  float v1 = st1[64 + d] * invN - mu1 * mu1;
  float h1 = (z1[idx] - mu1) * rsqrtf(v1 + 1e-5f) * g1[d] + b1[d];
  float mu2 = st2[d] * invN;
  float v2 = st2[64 + d] * invN - mu2 * mu2;
  float h2 = (z2[idx] - mu2) * rsqrtf(v2 + 1e-5f) * g2[d] + b2[d];
  comb[idx] = h1 + h2;
}

// ---------------- K row-norm max per head ----------------
__global__ void knorm_kernel(const float* __restrict__ qkv, int* __restrict__ kmax) {
  __shared__ int lmax[4];
  int tid = threadIdx.x;
  if (tid < 4) lmax[tid] = 0;
  __syncthreads();
  int idx = blockIdx.x * 256 + tid;   // (j, h): 16384 items
  int j = idx >> 2, h = idx & 3;
  const float* kr = qkv + (size_t)j * 192 + 64 + h * 16;
  float n2 = 0.f;
#pragma unroll
  for (int c = 0; c < 16; ++c) { float v = kr[c]; n2 = fmaf(v, v, n2); }
  atomicMax(&lmax[h], __float_as_int(sqrtf(n2)));
  __syncthreads();
  if (tid < 4) atomicMax(&kmax[tid], lmax[tid]);
}

// ---------------- flash attention f16-dot2, fixed shift, j-split 8 ----------------
// grid (N/64, H, 8), block 256 (4 waves). lane = row, waves stride over j-pairs.
#define TJ 256
__global__ void attn_kernel(const float* __restrict__ qkv, const int* __restrict__ kmax,
                            float* __restrict__ accS, float* __restrict__ accO) {
  __shared__ __align__(16) float smem[4416];
  uint4* kt = (uint4*)smem;            // [TJ][2] : K rows as 8 half2
  uint4* vt = (uint4*)(smem + 2048);   // [4][128]: V pair-chunks (c4, jpair)
  int h = blockIdx.y, js = blockIdx.z;
  int i0 = blockIdx.x * 64;
  int r = threadIdx.x & 63;
  int gq = threadIdx.x >> 6;
  int i = i0 + r;
  float qf[16];
  const float* qr = qkv + (size_t)i * 192 + h * 16;
#pragma unroll
  for (int c = 0; c < 16; ++c) qf[c] = qr[c] * 0.25f;
  float qn2 = 0.f;
#pragma unroll
  for (int c = 0; c < 16; ++c) qn2 = fmaf(qf[c], qf[c], qn2);
  float m = sqrtf(qn2) * __int_as_float(kmax[h]);  // >= max score (Cauchy-Schwarz; RTZ shrinks)
  h2_t q2[8];
#pragma unroll
  for (int c = 0; c < 8; ++c) q2[c] = __builtin_amdgcn_cvt_pkrtz(qf[2 * c], qf[2 * c + 1]);
  float s = 0.f;
  float acc[16];
#pragma unroll
  for (int c = 0; c < 16; ++c) acc[c] = 0.f;

  for (int t = 0; t < 2; ++t) {
    int j0 = js * 512 + t * TJ;
    __syncthreads();
    {
      int jj = threadIdx.x;
      const float* kr = qkv + (size_t)(j0 + jj) * 192 + 64 + h * 16;
      float4 a = *(const float4*)kr, b = *(const float4*)(kr + 4);
      float4 c4f = *(const float4*)(kr + 8), d4 = *(const float4*)(kr + 12);
      H2x4 w0, w1;
      w0.h[0] = __builtin_amdgcn_cvt_pkrtz(a.x, a.y); w0.h[1] = __builtin_amdgcn_cvt_pkrtz(a.z, a.w);
      w0.h[2] = __builtin_amdgcn_cvt_pkrtz(b.x, b.y); w0.h[3] = __builtin_amdgcn_cvt_pkrtz(b.z, b.w);
      w1.h[0] = __builtin_amdgcn_cvt_pkrtz(c4f.x, c4f.y); w1.h[1] = __builtin_amdgcn_cvt_pkrtz(c4f.z, c4f.w);
      w1.h[2] = __builtin_amdgcn_cvt_pkrtz(d4.x, d4.y); w1.h[3] = __builtin_amdgcn_cvt_pkrtz(d4.z, d4.w);
      kt[jj * 2] = w0.u; kt[jj * 2 + 1] = w1.u;
      for (int id = threadIdx.x; id < 512; id += 256) {
        int c4 = id & 3, jp = id >> 2;
        const float* va = qkv + (size_t)(j0 + 2 * jp) * 192 + 128 + h * 16 + c4 * 4;
        float4 A = *(const float4*)va, B = *(const float4*)(va + 192);
        H2x4 w;
        w.h[0] = __builtin_amdgcn_cvt_pkrtz(A.x, B.x); w.h[1] = __builtin_amdgcn_cvt_pkrtz(A.y, B.y);
        w.h[2] = __builtin_amdgcn_cvt_pkrtz(A.z, B.z); w.h[3] = __builtin_amdgcn_cvt_pkrtz(A.w, B.w);
        vt[c4 * 128 + jp] = w.u;
      }
    }
    __syncthreads();
    for (int jp = gq; jp < 128; jp += 4) {
      H2x4 ka0, ka1, kb0, kb1;
      ka0.u = kt[jp * 4 + 0]; ka1.u = kt[jp * 4 + 1];
      kb0.u = kt[jp * 4 + 2]; kb1.u = kt[jp * 4 + 3];
      float sa = 0.f, sb = 0.f;
#pragma unroll
      for (int c = 0; c < 4; ++c) {
        sa = __builtin_amdgcn_fdot2(q2[c], ka0.h[c], sa, false);
        sb = __builtin_amdgcn_fdot2(q2[c], kb0.h[c], sb, false);
      }
#pragma unroll
      for (int c = 0; c < 4; ++c) {
        sa = __builtin_amdgcn_fdot2(q2[4 + c], ka1.h[c], sa, false);
        sb = __builtin_amdgcn_fdot2(q2[4 + c], kb1.h[c], sb, false);
      }
      float pa = __expf(sa - m), pb = __expf(sb - m);
      s += pa + pb;
      h2_t pp = __builtin_amdgcn_cvt_pkrtz(pa, pb);
      H2x4 v0, v1, v2, v3;
      v0.u = vt[jp]; v1.u = vt[128 + jp]; v2.u = vt[256 + jp]; v3.u = vt[384 + jp];
#pragma unroll
      for (int c = 0; c < 4; ++c) {
        acc[c]      = __builtin_amdgcn_fdot2(pp, v0.h[c], acc[c], false);
        acc[4 + c]  = __builtin_amdgcn_fdot2(pp, v1.h[c], acc[4 + c], false);
        acc[8 + c]  = __builtin_amdgcn_fdot2(pp, v2.h[c], acc[8 + c], false);
        acc[12 + c] = __builtin_amdgcn_fdot2(pp, v3.h[c], acc[12 + c], false);
      }
    }
  }
  // block-combine 4 waves (pure sums: fixed m), then atomics
  __syncthreads();
  float* cb = smem;  // [4][17][64]
  cb[(gq * 17 + 16) * 64 + r] = s;
#pragma unroll
  for (int c = 0; c < 16; ++c) cb[(gq * 17 + c) * 64 + r] = acc[c];
  __syncthreads();
  if (gq == 0) {
    float S = 0.f;
#pragma unroll
    for (int g2 = 0; g2 < 4; ++g2) S += cb[(g2 * 17 + 16) * 64 + r];
    atomAddF(&accS[h * N_NODE + i], S);
#pragma unroll
    for (int c = 0; c < 16; ++c) {
      float A = 0.f;
#pragma unroll
      for (int g2 = 0; g2 < 4; ++g2) A += cb[(g2 * 17 + c) * 64 + r];
      atomAddF(&accO[(h * 16 + c) * N_NODE + i], A);
    }
  }
}

// o[i][d] = accO[d][i]/accS[h][i]; self-cleans accO/accS/kmax for next layer
__global__ void attn_norm_kernel(float* __restrict__ accO, float* __restrict__ accS,
                                 int* __restrict__ kmax, float* __restrict__ o) {
  int idx = blockIdx.x * 256 + threadIdx.x;
  int i = idx >> 6, d = idx & 63, h = d >> 4;
  o[idx] = accO[d * N_NODE + i] / accS[h * N_NODE + i];
  __syncthreads();
  accO[d * N_NODE + i] = 0.f;
  if ((d & 15) == 0) accS[h * N_NODE + i] = 0.f;
  if (idx < 4) kmax[idx] = 0;
}

// ---------------- global mean pool ----------------
__global__ void pool_kernel(const float* __restrict__ x, const int* __restrict__ batch,
                            float* __restrict__ pool, float* __restrict__ pcnt) {
  int idx = blockIdx.x * blockDim.x + threadIdx.x;
  if (idx >= N_NODE * DD) return;
  int i = idx >> 6, d = idx & 63;
  int g = batch[i];
  atomAddF(&pool[g * DD + d], x[idx]);
  if (d == 0) atomAddF(&pcnt[g], 1.0f);
}

// ---------------- final linear + log_softmax ----------------
__global__ void final_kernel(const float* __restrict__ pool, const float* __restrict__ pcnt,
                             const float* __restrict__ fw, const float* __restrict__ fb,
                             float* __restrict__ out) {
  int g = blockIdx.x;
  int d = threadIdx.x;  // 64 threads
  __shared__ float mean[64];
  __shared__ float lg[16];
  float c = fmaxf(pcnt[g], 1.0f);
  mean[d] = pool[g * DD + d] / c;
  __syncthreads();
  if (d < 10) {
    float acc = fb[d];
#pragma unroll 8
    for (int k = 0; k < 64; ++k) acc += mean[k] * fw[k * 10 + d];
    lg[d] = acc;
  }
  __syncthreads();
  if (d == 0) {
    float mx = -INFINITY;
    for (int c2 = 0; c2 < 10; ++c2) mx = fmaxf(mx, lg[c2]);
    float sum = 0.f;
    for (int c2 = 0; c2 < 10; ++c2) sum += expf(lg[c2] - mx);
    lg[10] = mx + logf(sum);
  }
  __syncthreads();
  if (d < 10) out[g * 10 + d] = lg[d] - lg[10];
}

// ---------------- host side ----------------
static void run_linear(const float* A, const float* W, const float* b, float* C,
                       float* C2, int split, const float* resid,
                       int K, int Nc, int act, int R, hipStream_t s) {
  int block = Nc * R;
  int grid = N_NODE / R;
  hipLaunchKernelGGL(linear_kernel, dim3(grid), dim3(block), R * K * sizeof(float), s,
                     A, W, b, C, C2, split, resid, K, Nc, act);
}

extern "C" void kernel_launch(void* const* d_in, const int* in_sizes, int n_in,
                              void* d_out, int out_size, void* d_ws, size_t ws_size,
                              hipStream_t stream) {
  const float* x_in      = (const float*)d_in[0];
  const int*   edge_idx  = (const int*)d_in[1];
  const int*   batch     = (const int*)d_in[2];
  const float* pre_w1    = (const float*)d_in[3];
  const float* pre_b1    = (const float*)d_in[4];
  const float* pre_w2    = (const float*)d_in[5];
  const float* pre_b2    = (const float*)d_in[6];
  const float* gat_wl    = (const float*)d_in[7];
  const float* gat_bl    = (const float*)d_in[8];
  const float* gat_wr    = (const float*)d_in[9];
  const float* gat_br    = (const float*)d_in[10];
  const float* gat_att   = (const float*)d_in[11];
  const float* gat_bias  = (const float*)d_in[12];
  const float* attn_in_w = (const float*)d_in[13];
  const float* attn_in_b = (const float*)d_in[14];
  const float* attn_out_w= (const float*)d_in[15];
  const float* attn_out_b= (const float*)d_in[16];
  const float* bn1_g     = (const float*)d_in[17];
  const float* bn1_b     = (const float*)d_in[18];
  const float* bn2_g     = (const float*)d_in[19];
  const float* bn2_b     = (const float*)d_in[20];
  const float* bn3_g     = (const float*)d_in[21];
  const float* bn3_b     = (const float*)d_in[22];
  const float* mlp_w1    = (const float*)d_in[23];
  const float* mlp_b1    = (const float*)d_in[24];
  const float* mlp_w2    = (const float*)d_in[25];
  const float* mlp_b2    = (const float*)d_in[26];
  const float* fin_w     = (const float*)d_in[27];
  const float* fin_b     = (const float*)d_in[28];
  float* out = (float*)d_out;

  // workspace layout (floats)
  float* ws = (float*)d_ws;
  float* xbuf  = ws;                    // 262144
  float* qkv   = xbuf + 262144;         // 786432
  float* xlr   = qkv + 786432;          // 524288 (pre1 hid too)
  float* hid   = xlr + 524288;          // 524288: obuf = hid[0:262144], z1 = hid[262144:]
  float* obuf  = hid;
  float* z1    = hid + 262144;
  float* z2    = hid + 524288;          // 262144 (also z3)
  float* comb  = z2 + 262144;           // 262144
  float* cw    = comb + 262144;         // 61440
  float* cbias = cw + 61440;            // 960
  float* tout  = cbias + 960;           // 12288
  // ---- contiguous zero region (single memset per launch) ----
  float* zr    = tout + 12288;
  int*   cnt   = (int*)zr;              // 4096
  float* stats = zr + 4096;             // 1152 (9 x 128)
  float* pool  = stats + 1152;          // 4096
  float* pcnt  = pool + 4096;           // 64
  int*   kmax  = (int*)(pcnt + 64);     // 4
  float* accS  = (float*)(kmax + 4);    // 16384
  float* accO  = accS + 16384;          // 262144
  size_t zr_elems = 4096 + 1152 + 4096 + 64 + 4 + 16384 + 262144;
  float* zend  = accO + 262144;
  int* row_ptr = (int*)zend;            // 4097
  int* nextp   = row_ptr + 4097;        // 4096
  int* csr_src = nextp + 4096;          // 266240

  hipMemsetAsync(zr, 0, zr_elems * sizeof(float), stream);

  // ---- CSR build ----
  hipLaunchKernelGGL(csr_count_kernel, dim3((E_TOT + 255) / 256), dim3(256), 0, stream,
                     edge_idx, cnt);
  hipLaunchKernelGGL(csr_scan_kernel, dim3(1), dim3(256), 0, stream, cnt, row_ptr, nextp);
  hipLaunchKernelGGL(csr_fill_kernel, dim3((E_TOT + 255) / 256), dim3(256), 0, stream,
                     edge_idx, nextp, csr_src);

  // ---- combined weights (once) ----
  hipLaunchKernelGGL(build_w_kernel, dim3((NL * 64 * 320 + 255) / 256), dim3(256), 0, stream,
                     gat_wl, gat_bl, gat_wr, gat_br, attn_in_w, attn_in_b, attn_out_w,
                     cw, cbias, tout);

  // ---- preprocess MLP ----
  run_linear(x_in, pre_w1, pre_b1, xlr, nullptr, 128, nullptr, 9, 128, 1, 2, stream);
  run_linear(xlr, pre_w2, pre_b2, xbuf, nullptr, 64, nullptr, 128, 64, 1, 4, stream);

  for (int l = 0; l < NL; ++l) {
    const float* attv = gat_att + l * DD;
    const float* gbias = gat_bias + l * DD;
    float* st1 = stats + (l * 3 + 0) * 128;
    float* st2 = stats + (l * 3 + 1) * 128;
    float* st3 = stats + (l * 3 + 2) * 128;

    // fused xl|xr|qkv linear: 64 -> 320
    run_linear(xbuf, cw + l * 20480, cbias + l * 320, xlr, qkv, 128, nullptr,
               64, 320, 0, 2, stream);

    // global attention (f16 dot2)
    hipLaunchKernelGGL(knorm_kernel, dim3(64), dim3(256), 0, stream, qkv, kmax);
    hipLaunchKernelGGL(attn_kernel, dim3(N_NODE / 64, 4, 8), dim3(256), 0, stream,
                       qkv, kmax, accS, accO);
    hipLaunchKernelGGL(attn_norm_kernel, dim3(N_NODE * DD / 256), dim3(256), 0, stream,
                       accO, accS, kmax, obuf);

    // local GATv2
    hipLaunchKernelGGL(gat_agg_kernel, dim3(N_NODE / 4), dim3(256), 0, stream,
                       xbuf, xlr, attv, gbias, row_ptr, csr_src, z1);
    hipLaunchKernelGGL(colstats_kernel, dim3(32), dim3(256), 0, stream, z1, st1);

    // out-proj + resid x
    run_linear(obuf, tout + l * 4096, attn_out_b + l * DD, z2, nullptr, 64, xbuf,
               64, 64, 0, 4, stream);
    hipLaunchKernelGGL(colstats_kernel, dim3(32), dim3(256), 0, stream, z2, st2);

    // comb = bn1(z1) + bn2(z2)
    hipLaunchKernelGGL(bnbn_kernel, dim3(N_NODE * DD / 256), dim3(256), 0, stream,
                       z1, st1, bn1_g + l * DD, bn1_b + l * DD,
                       z2, st2, bn2_g + l * DD, bn2_b + l * DD, comb);

    // MLP
    run_linear(comb, mlp_w1 + l * 8192, mlp_b1 + l * 128, hid, nullptr, 128, nullptr,
               64, 128, 2, 2, stream);
    run_linear(hid, mlp_w2 + l * 8192, mlp_b2 + l * DD, z2, nullptr, 64, comb,
               128, 64, 0, 4, stream);
    hipLaunchKernelGGL(colstats_kernel, dim3(32), dim3(256), 0, stream, z2, st3);
    hipLaunchKernelGGL(bn_apply_kernel, dim3(N_NODE * DD / 256), dim3(256), 0, stream,
                       z2, st3, bn3_g + l * DD, bn3_b + l * DD, xbuf, 1);
  }

  // ---- pool + final ----
  hipLaunchKernelGGL(pool_kernel, dim3(N_NODE * DD / 256), dim3(256), 0, stream,
                     xbuf, batch, pool, pcnt);
  hipLaunchKernelGGL(final_kernel, dim3(NG), dim3(64), 0, stream, pool, pcnt, fin_w, fin_b, out);
}